// Round 2
// baseline (268.606 us; speedup 1.0000x reference)
//
#include <hip/hip_runtime.h>

// ---------- problem constants ----------
#define BATCH   16
#define LIN     320000
#define LP      322048          // LIN + 2048 (reflect pad 1024 each side)
#define TFR     626             // frames per batch
#define MTOT    (BATCH*TFR)     // 10016
#define KD      2048            // N_FFT
#define KOUT    1025            // N_FFT/2+1
#define ND      (2*KOUT)        // 2050 (real | imag)
#define NPAD    2176            // ND padded up to multiple of 128
#define IMAG_OFF (MTOT*(long)KOUT)   // 10266400

typedef __attribute__((ext_vector_type(8))) short short8;
typedef __attribute__((ext_vector_type(4))) float float4v;
typedef unsigned short ushort_t;

static __device__ __forceinline__ ushort_t f32_to_bf16(float f) {
    union { float f; unsigned u; } un; un.f = f;
    unsigned r = un.u + 0x7fffu + ((un.u >> 16) & 1u);   // RNE
    return (ushort_t)(r >> 16);
}

static __device__ __forceinline__ void async_copy16(const void* g, void* l) {
    __builtin_amdgcn_global_load_lds(
        (const __attribute__((address_space(1))) void*)g,
        (__attribute__((address_space(3))) void*)l, 16, 0, 0);
}

// ---------- prepass 1: reflect-pad fp32 x -> bf16 xp (BATCH x LP) ----------
__global__ void build_xp(const float* __restrict__ x, ushort_t* __restrict__ xp) {
    int i = blockIdx.x * 256 + threadIdx.x;      // grid sized exactly
    int b = i / LP;
    int p = i - b * LP;
    int j = p - 1024;
    if (j < 0) j = -j;
    else if (j >= LIN) j = 2*LIN - 2 - j;
    xp[i] = f32_to_bf16(x[b * LIN + j]);
}

// ---------- prepass 2: pack W^T n-major as bf16: WbT[n][k], n in [0,NPAD) ----
// 32x32 LDS-tiled transpose: fp32 reads coalesced along n, writes coalesced
// along k. grid = (NPAD/32, KD/32), block = 256 (32 wide x 8 tall x 4 iters).
__global__ void build_wbt(const float* __restrict__ wr,
                          const float* __restrict__ wi,
                          ushort_t* __restrict__ wbt) {
    __shared__ ushort_t tile[32][33];
    const int n0 = blockIdx.x * 32;
    const int k0 = blockIdx.y * 32;
    const int tx = threadIdx.x & 31;
    const int ty = threadIdx.x >> 5;             // 0..7
    const int n = n0 + tx;
#pragma unroll
    for (int i = 0; i < 4; ++i) {
        int k = k0 + ty + i * 8;
        float v;
        if (n < KOUT)      v = wr[k * KOUT + n];
        else if (n < ND)   v = wi[k * KOUT + (n - KOUT)];
        else               v = 0.f;
        tile[ty + i * 8][tx] = f32_to_bf16(v);
    }
    __syncthreads();
#pragma unroll
    for (int i = 0; i < 4; ++i) {
        int nn = n0 + ty + i * 8;
        int kk = k0 + tx;
        wbt[nn * KD + kk] = tile[tx][ty + i * 8];
    }
}

// ---------- main GEMM: C[M,N] = frames * W ; 128x128 tile, BK=32 ----------
__global__ __launch_bounds__(256) void stft_gemm(const ushort_t* __restrict__ xp,
                                                 const ushort_t* __restrict__ wbt,
                                                 float* __restrict__ out) {
    __shared__ __align__(16) ushort_t As[128 * 32];   // row-major [m][k]
    __shared__ __align__(16) ushort_t Bs[128 * 32];   // n-major   [n][k]

    const int tid = threadIdx.x;
    const int m0 = blockIdx.y * 128;
    const int n0 = blockIdx.x * 128;

    // --- staging source addresses (element offsets), fixed per thread ---
    const int r  = tid >> 2;            // 0..63 (row within 64-row chunk)
    const int c8 = (tid & 3) * 8;       // k offset
    int baseA[2], baseB[2];
#pragma unroll
    for (int i = 0; i < 2; ++i) {
        int m = m0 + i * 64 + r;
        if (m > MTOT - 1) m = MTOT - 1;           // clamp; store is guarded
        int b = m / TFR;
        int t = m - b * TFR;
        baseA[i] = b * LP + t * 512 + c8;
        int n = n0 + i * 64 + r;                  // < NPAD always
        baseB[i] = n * KD + c8;
    }
    char* ldsA = (char*)As + tid * 16;
    char* ldsB = (char*)Bs + tid * 16;

    // --- wave/lane geometry ---
    const int wave = tid >> 6;
    const int lane = tid & 63;
    const int wm = (wave >> 1) * 64;
    const int wn = (wave & 1) * 64;
    const int lm = lane & 15;
    const int quad = lane >> 4;

    float4v acc[4][4];
#pragma unroll
    for (int mi = 0; mi < 4; ++mi)
#pragma unroll
        for (int ni = 0; ni < 4; ++ni)
            acc[mi][ni] = (float4v){0.f, 0.f, 0.f, 0.f};

    for (int k0 = 0; k0 < KD; k0 += 32) {
        __syncthreads();                           // prior reads done
#pragma unroll
        for (int i = 0; i < 2; ++i)
            async_copy16(xp + baseA[i] + k0, ldsA + i * 4096);
#pragma unroll
        for (int i = 0; i < 2; ++i)
            async_copy16(wbt + baseB[i] + k0, ldsB + i * 4096);
        __syncthreads();                           // drains vmcnt

        short8 af[4], bf[4];
#pragma unroll
        for (int mi = 0; mi < 4; ++mi)
            af[mi] = *(const short8*)&As[(wm + mi * 16 + lm) * 32 + quad * 8];
#pragma unroll
        for (int ni = 0; ni < 4; ++ni)
            bf[ni] = *(const short8*)&Bs[(wn + ni * 16 + lm) * 32 + quad * 8];
#pragma unroll
        for (int mi = 0; mi < 4; ++mi)
#pragma unroll
            for (int ni = 0; ni < 4; ++ni)
                acc[mi][ni] = __builtin_amdgcn_mfma_f32_16x16x32_bf16(
                    af[mi], bf[ni], acc[mi][ni], 0, 0, 0);
    }

    // --- epilogue: C/D layout col=lane&15, row=quad*4+reg ; fp32 out ---
#pragma unroll
    for (int mi = 0; mi < 4; ++mi) {
#pragma unroll
        for (int ni = 0; ni < 4; ++ni) {
            int n = n0 + wn + ni * 16 + lm;
            if (n >= ND) continue;
            long nbase = (n < KOUT) ? (long)n : (IMAG_OFF + (n - KOUT));
#pragma unroll
            for (int rg = 0; rg < 4; ++rg) {
                int m = m0 + wm + mi * 16 + quad * 4 + rg;
                if (m < MTOT)
                    out[nbase + (long)m * KOUT] = acc[mi][ni][rg];
            }
        }
    }
}

extern "C" void kernel_launch(void* const* d_in, const int* in_sizes, int n_in,
                              void* d_out, int out_size, void* d_ws, size_t ws_size,
                              hipStream_t stream) {
    const float* x  = (const float*)d_in[0];     // fp32 (16, 320000)
    const float* wr = (const float*)d_in[1];     // fp32 (2048, 1025)
    const float* wi = (const float*)d_in[2];     // fp32 (2048, 1025)
    float* out = (float*)d_out;                  // fp32, 2*16*626*1025

    ushort_t* xp  = (ushort_t*)d_ws;             // 16*322048 bf16 = 10.3 MB
    ushort_t* wbt = xp + BATCH * LP;             // 2176*2048 bf16 =  8.9 MB

    build_xp <<<(BATCH * LP) / 256, 256, 0, stream>>>(x, xp);
    dim3 tgrid(NPAD / 32, KD / 32);              // 68 x 64
    build_wbt<<<tgrid, 256, 0, stream>>>(wr, wi, wbt);

    dim3 grid(NPAD / 128, (MTOT + 127) / 128);   // 17 x 79
    stft_gemm<<<grid, 256, 0, stream>>>(xp, wbt, out);
}